// Round 4
// baseline (109.824 us; speedup 1.0000x reference)
//
#include <hip/hip_runtime.h>
#include <hip/hip_bf16.h>

#define B 32
#define S 8192
#define D 512
#define CODE_START 256
#define CODE_END 257
#define MEM_TOK 258
#define ADDR_KEY 206
#define MEM_STORE 455
#define CHUNK 512
#define NCH (S / CHUNK)  // 16 chunks per row

typedef float f32x4 __attribute__((ext_vector_type(4)));

// ---------------------------------------------------------------------------
// Kernel A: per-chunk local scan. Grid (NCH, B), 256 threads, 2 tokens/thread.
// Writes: cs_local[b][s] (inclusive chunk-local max CODE_START pos),
//         carry[b][c] (chunk max), mince[b][c] (chunk min CODE_END pos).
// ---------------------------------------------------------------------------
__global__ __launch_bounds__(256) void nvm_chunk_scan(
    const int* __restrict__ tok, int* __restrict__ cs_local,
    int* __restrict__ carry, int* __restrict__ mince) {
  const int c = blockIdx.x;
  const int b = blockIdx.y;
  const int tid = threadIdx.x;
  const int lane = tid & 63;
  const int wid = tid >> 6;
  const int base = c * CHUNK;
  const int* row = tok + b * S;

  const int s0 = base + 2 * tid, s1 = s0 + 1;
  const int t0 = row[s0], t1 = row[s1];
  int v0 = (t0 == CODE_START) ? s0 : -1;
  int v1 = (t1 == CODE_START) ? s1 : -1;
  const int i1 = max(v0, v1);  // pair-inclusive

  // wave-64 inclusive max scan over pair totals
  int incl = i1;
  #pragma unroll
  for (int off = 1; off < 64; off <<= 1) {
    int u = __shfl_up(incl, off, 64);
    if (lane >= off) incl = max(incl, u);
  }
  int ex = __shfl_up(incl, 1, 64);
  if (lane == 0) ex = -1;

  // min CODE_END reduce
  int m = min((t0 == CODE_END) ? s0 : S, (t1 == CODE_END) ? s1 : S);
  #pragma unroll
  for (int off = 32; off; off >>= 1) m = min(m, __shfl_down(m, off, 64));

  __shared__ int wt[4], wm[4];
  if (lane == 63) wt[wid] = incl;
  if (lane == 0) wm[wid] = m;
  __syncthreads();

  int pre = -1;
  for (int w = 0; w < wid; ++w) pre = max(pre, wt[w]);
  ex = max(ex, pre);
  cs_local[b * S + s0] = max(ex, v0);
  cs_local[b * S + s1] = max(ex, i1);

  if (tid == 0) {
    carry[b * NCH + c] = max(max(wt[0], wt[1]), max(wt[2], wt[3]));
    mince[b * NCH + c] = min(min(wm[0], wm[1]), min(wm[2], wm[3]));
  }
}

// ---------------------------------------------------------------------------
// Kernel M: per-block LDS build of chunk-prefix/fce, then gather + patch +
// nontemporal stream out. 128 threads per token (one float4 each),
// 2 tokens per block-iteration, grid-stride over token pairs.
// ---------------------------------------------------------------------------
__global__ __launch_bounds__(256) void nvm_main(
    const int* __restrict__ tok, const float* __restrict__ table,
    const int* __restrict__ cs_local, const int* __restrict__ carry,
    const int* __restrict__ mince, const int* __restrict__ mhe_p,
    float* __restrict__ out) {
  __shared__ int pre_sh[B * NCH];
  __shared__ int fce_sh[B];

  // Build exclusive prefix-max of carries + fce per row (2 KB inputs, L2-hot).
  for (int i = threadIdx.x; i < B * NCH; i += 256) {
    const int b = i >> 4, c = i & (NCH - 1);
    int run = -1;
    for (int c2 = 0; c2 < c; ++c2) run = max(run, carry[(b << 4) + c2]);
    pre_sh[i] = run;
  }
  if (threadIdx.x < B) {
    int mn = S;
    #pragma unroll
    for (int c2 = 0; c2 < NCH; ++c2) mn = min(mn, mince[(threadIdx.x << 4) + c2]);
    fce_sh[threadIdx.x] = mn;
  }
  __syncthreads();

  const int lane = threadIdx.x & 127;
  const int half = threadIdx.x >> 7;
  const int mhe = mhe_p[0];
  const int NTP = B * S / 2;
  const int c0 = lane * 4;

  for (int tp = blockIdx.x; tp < NTP; tp += gridDim.x) {
    const int t = tp * 2 + half;
    const int b = t >> 13;
    const int s = t & (S - 1);

    const int tk = tok[t];
    const int cs = max(cs_local[t], pre_sh[(b << 4) + (s >> 9)]);
    const int f = fce_sh[b];

    const bool maskAddr = (cs >= 0) && (s < f) && (tk < 256);
    int c1 = -1, c2 = -1, c3 = -1;
    if (maskAddr) {
      int sp = s - cs - 1;
      if (sp < 0) sp = 0;
      int q = sp / 5;
      int r = sp - q * 5;
      int addr = q * 8 + r;
      c1 = ADDR_KEY + (addr & 15);
      c2 = ADDR_KEY + 16 + ((addr >> 4) & 15);
      c3 = ADDR_KEY + 32 + ((addr >> 8) & 15);
    }
    const bool memM = (tk == MEM_TOK) && (s < mhe);

    f32x4 v = *reinterpret_cast<const f32x4*>(table + tk * D + c0);
    #pragma unroll
    for (int j = 0; j < 4; ++j) {
      int ch = c0 + j;
      bool hit = (maskAddr && (ch == c1 || ch == c2 || ch == c3)) ||
                 (memM && ch == MEM_STORE);
      if (hit) v[j] = 1.0f;
    }
    f32x4* dst = reinterpret_cast<f32x4*>(out + (size_t)t * D + c0);
    __builtin_nontemporal_store(v, dst);
  }
}

extern "C" void kernel_launch(void* const* d_in, const int* in_sizes, int n_in,
                              void* d_out, int out_size, void* d_ws, size_t ws_size,
                              hipStream_t stream) {
  const int* tok = (const int*)d_in[0];
  const float* table = (const float*)d_in[1];
  const int* mhe = (const int*)d_in[2];
  float* out = (float*)d_out;

  int* cs_local = (int*)d_ws;                 // B*S ints = 1 MiB
  int* carry = cs_local + B * S;              // B*NCH
  int* mince = carry + B * NCH;               // B*NCH

  nvm_chunk_scan<<<dim3(NCH, B), 256, 0, stream>>>(tok, cs_local, carry, mince);
  nvm_main<<<4096, 256, 0, stream>>>(tok, table, cs_local, carry, mince, mhe, out);
}